// Round 1
// baseline (120.770 us; speedup 1.0000x reference)
//
#include <hip/hip_runtime.h>

typedef __bf16 bf16x8 __attribute__((ext_vector_type(8)));
typedef float  f32x4  __attribute__((ext_vector_type(4)));
typedef unsigned short ushort_t;

#define T_LEN 128
#define BATCH 64
#define M_TOK 8192   // BATCH * T_LEN
#define HDIM  128
#define BR 64        // rows per block (kernel B)
#define BC 64        // cols per j-iteration
#define JSPLIT 8
#define SB_STRIDE 136  // 128 + 8 halfword pad -> row stride 272 B, breaks bank aliasing

// round-to-nearest-even fp32 -> bf16
__device__ inline ushort_t f2bf(float f) {
    unsigned int u = __float_as_uint(f);
    unsigned int r = (u + 0x7FFFu + ((u >> 16) & 1u)) >> 16;
    return (ushort_t)r;
}

// Kernel A: one wave (64 lanes) per token row. Convert to bf16 and compute
// pos_i = dot(x_{i-1},x_i)[t>0] + dot(x_i,x_{i+1})[t<T-1] in fp32.
__global__ __launch_bounds__(64) void prep_kernel(const float* __restrict__ hs,
                                                  ushort_t* __restrict__ xbf,
                                                  float* __restrict__ pos) {
    int i = blockIdx.x;
    int lane = threadIdx.x;
    int t = i & (T_LEN - 1);
    const float* row = hs + (long)i * HDIM;
    float x0 = row[lane];
    float x1 = row[lane + 64];
    xbf[(long)i * HDIM + lane]      = f2bf(x0);
    xbf[(long)i * HDIM + lane + 64] = f2bf(x1);
    float acc = 0.f;
    if (t > 0) {
        const float* p = row - HDIM;
        acc += x0 * p[lane] + x1 * p[lane + 64];
    }
    if (t < T_LEN - 1) {
        const float* n = row + HDIM;
        acc += x0 * n[lane] + x1 * n[lane + 64];
    }
    for (int m = 32; m; m >>= 1) acc += __shfl_xor(acc, m);
    if (lane == 0) pos[i] = acc;
}

// Kernel B: grid (M_TOK/BR, JSPLIT), block 256 = 4 waves.
// Wave w owns 16 rows; block covers 1/JSPLIT of the 8192 columns.
// part[jy][row] = sum over that column slice of exp(x_row . x_col)
__global__ __launch_bounds__(256) void negsum_kernel(const ushort_t* __restrict__ xbf,
                                                     float* __restrict__ part) {
    __shared__ __align__(16) ushort_t sB[BC][SB_STRIDE];
    int tid  = threadIdx.x;
    int wave = tid >> 6;
    int lane = tid & 63;
    int col  = lane & 15;
    int quad = lane >> 4;
    int row0 = blockIdx.x * BR + wave * 16;
    int jy   = blockIdx.y;

    // A fragments: invariant across the j loop.
    // lane holds A[m=lane&15][k = k4*32 + quad*8 + (0..7)]
    bf16x8 afr[4];
    {
        const ushort_t* ap = xbf + (long)(row0 + col) * HDIM + quad * 8;
        #pragma unroll
        for (int k4 = 0; k4 < 4; ++k4)
            afr[k4] = *(const bf16x8*)(ap + k4 * 32);
    }

    float rs[4] = {0.f, 0.f, 0.f, 0.f};
    const int jiters = M_TOK / (JSPLIT * BC);   // 16

    for (int jt = 0; jt < jiters; ++jt) {
        int jbase = jy * (M_TOK / JSPLIT) + jt * BC;
        __syncthreads();
        // stage 64 rows x 128 halfwords of X into LDS (each thread: 64 B)
        {
            int r = tid >> 2;
            int c = (tid & 3) * 32;
            const uint4* src = (const uint4*)(xbf + (long)(jbase + r) * HDIM + c);
            uint4* dst = (uint4*)(&sB[r][c]);
            #pragma unroll
            for (int q = 0; q < 4; ++q) dst[q] = src[q];
        }
        __syncthreads();

        #pragma unroll
        for (int nt = 0; nt < 4; ++nt) {
            const ushort_t* bp = &sB[nt * 16 + col][quad * 8];
            f32x4 d = {0.f, 0.f, 0.f, 0.f};
            #pragma unroll
            for (int k4 = 0; k4 < 4; ++k4) {
                bf16x8 bfr = *(const bf16x8*)(bp + k4 * 32);
                d = __builtin_amdgcn_mfma_f32_16x16x32_bf16(afr[k4], bfr, d, 0, 0, 0);
            }
            // d[r] = x_{row0+quad*4+r} . x_{jbase+nt*16+col}
            rs[0] += __expf(d[0]);
            rs[1] += __expf(d[1]);
            rs[2] += __expf(d[2]);
            rs[3] += __expf(d[3]);
        }
    }

    // reduce across the 16 column-lanes within each quad group
    #pragma unroll
    for (int m = 1; m < 16; m <<= 1) {
        #pragma unroll
        for (int r = 0; r < 4; ++r) rs[r] += __shfl_xor(rs[r], m);
    }
    if (col == 0) {
        #pragma unroll
        for (int r = 0; r < 4; ++r)
            part[(long)jy * M_TOK + row0 + quad * 4 + r] = rs[r];
    }
}

// Kernel C: single block; loss = sum_{valid} (log(neg_i) - pos_i) / Nvalid
__global__ __launch_bounds__(256) void finalize_kernel(const float* __restrict__ part,
                                                       const float* __restrict__ pos,
                                                       const int* __restrict__ dia,
                                                       float* __restrict__ out) {
    __shared__ float sred[256];
    __shared__ int scnt;
    int tid = threadIdx.x;
    if (tid == 0) {
        int c = 0;
        for (int b = 0; b < BATCH; ++b) c += dia[b] - 1;
        scnt = c;
    }
    float acc = 0.f;
    for (int i = tid; i < M_TOK; i += 256) {
        int b = i >> 7;
        int t = i & (T_LEN - 1);
        int len = dia[b];
        if (t < len - 1) {
            float ns = 0.f;
            #pragma unroll
            for (int p = 0; p < JSPLIT; ++p) ns += part[(long)p * M_TOK + i];
            acc += logf(ns) - pos[i];
        }
    }
    sred[tid] = acc;
    __syncthreads();
    for (int s = 128; s; s >>= 1) {
        if (tid < s) sred[tid] += sred[tid + s];
        __syncthreads();
    }
    if (tid == 0) out[0] = sred[0] / (float)scnt;
}

extern "C" void kernel_launch(void* const* d_in, const int* in_sizes, int n_in,
                              void* d_out, int out_size, void* d_ws, size_t ws_size,
                              hipStream_t stream) {
    const float* hs  = (const float*)d_in[0];
    // d_in[1] = mask (recomputed from dia_lens; unused)
    const int*   dia = (const int*)d_in[2];
    float* out = (float*)d_out;

    ushort_t* xbf = (ushort_t*)d_ws;                               // 2 MB
    float* pos    = (float*)((char*)d_ws + 2097152);               // 32 KB
    float* part   = (float*)((char*)d_ws + 2097152 + 32768);       // 256 KB

    prep_kernel<<<M_TOK, 64, 0, stream>>>(hs, xbf, pos);
    negsum_kernel<<<dim3(M_TOK / BR, JSPLIT), 256, 0, stream>>>(xbf, part);
    finalize_kernel<<<1, 256, 0, stream>>>(part, pos, dia, out);
}

// Round 2
// 89.404 us; speedup vs baseline: 1.3508x; 1.3508x over previous
//
#include <hip/hip_runtime.h>

typedef __bf16 bf16x8 __attribute__((ext_vector_type(8)));
typedef float  f32x4  __attribute__((ext_vector_type(4)));
typedef unsigned short ushort_t;

#define T_LEN 128
#define BATCH 64
#define M_TOK 8192   // BATCH * T_LEN
#define HDIM  128
#define JSPLIT 32
#define SQRT_LOG2E 1.2011224087864498f  // sqrt(log2(e)); (s*x_i).(s*x_j) = log2(e)*x_i.x_j

// round-to-nearest-even fp32 -> bf16
__device__ inline ushort_t f2bf(float f) {
    unsigned int u = __float_as_uint(f);
    unsigned int r = (u + 0x7FFFu + ((u >> 16) & 1u)) >> 16;
    return (ushort_t)r;
}

// Kernel A: 2048 blocks x 256 threads; wave w handles row blockIdx*4+w.
// Converts to bf16 (pre-scaled by sqrt(log2 e)) and computes fp32-exact pos_i.
// Also zeroes part[] (consumed via atomicAdd by negsum).
__global__ __launch_bounds__(256) void prep_kernel(const float* __restrict__ hs,
                                                   ushort_t* __restrict__ xbf,
                                                   float* __restrict__ pos,
                                                   float* __restrict__ part) {
    int wave = threadIdx.x >> 6;
    int lane = threadIdx.x & 63;
    int i = blockIdx.x * 4 + wave;
    int t = i & (T_LEN - 1);
    const float* row = hs + (size_t)i * HDIM;
    float x0 = row[lane];
    float x1 = row[lane + 64];
    xbf[(size_t)i * HDIM + lane]      = f2bf(x0 * SQRT_LOG2E);
    xbf[(size_t)i * HDIM + lane + 64] = f2bf(x1 * SQRT_LOG2E);
    float acc = 0.f;
    if (t > 0) {
        const float* p = row - HDIM;
        acc += x0 * p[lane] + x1 * p[lane + 64];
    }
    if (t < T_LEN - 1) {
        const float* n = row + HDIM;
        acc += x0 * n[lane] + x1 * n[lane + 64];
    }
    for (int m = 32; m; m >>= 1) acc += __shfl_xor(acc, m);
    if (lane == 0) pos[i] = acc;
    if (threadIdx.x < 4) part[blockIdx.x * 4 + threadIdx.x] = 0.f;
}

// Kernel B: grid (32, 32), block 256 = 4 waves. Wave owns 64 rows (4 A-frag
// sets, j-invariant, register-resident); block covers a 256-column slice.
// Each B fragment from LDS feeds 4 MFMAs. LDS uses 16B-block XOR swizzle
// (by row&7, stride 128 halfwords) -> uniform bank-group distribution.
// part[row] += sum_j exp2(score) via atomicAdd (fp reorder noise << thresh).
__global__ __launch_bounds__(256, 4) void negsum_kernel(const ushort_t* __restrict__ xbf,
                                                        float* __restrict__ part) {
    __shared__ __align__(16) ushort_t sB[64 * 128];  // 16 KB, swizzled
    int tid  = threadIdx.x;
    int wave = tid >> 6;
    int lane = tid & 63;
    int col  = lane & 15;
    int quad = lane >> 4;
    int rowbase = blockIdx.x * 256 + wave * 64;
    int gy = blockIdx.y;

    // A fragments: lane holds A[m=lane&15][k=quad*8 + k4*32 + (0..7)]
    bf16x8 afr[4][4];
    #pragma unroll
    for (int rb = 0; rb < 4; ++rb) {
        const ushort_t* ap = xbf + (size_t)(rowbase + rb * 16 + col) * HDIM + quad * 8;
        #pragma unroll
        for (int k4 = 0; k4 < 4; ++k4)
            afr[rb][k4] = *(const bf16x8*)(ap + k4 * 32);
    }

    float rs[4][4];
    #pragma unroll
    for (int rb = 0; rb < 4; ++rb)
        #pragma unroll
        for (int r = 0; r < 4; ++r) rs[rb][r] = 0.f;

    for (int jt = 0; jt < 4; ++jt) {
        int jbase = gy * 256 + jt * 64;
        __syncthreads();
        // stage 64 rows x 256B into LDS, 64B/thread, swizzled 16B blocks
        {
            int r  = tid >> 2;
            int cb = (tid & 3) * 4;
            const uint4* src = (const uint4*)(xbf + (size_t)(jbase + r) * HDIM + cb * 8);
            #pragma unroll
            for (int q = 0; q < 4; ++q) {
                int c = cb + q;
                *(uint4*)(&sB[r * 128 + ((c ^ (r & 7)) << 3)]) = src[q];
            }
        }
        __syncthreads();

        #pragma unroll
        for (int nt = 0; nt < 4; ++nt) {
            int br = nt * 16 + col;   // B row (gram column) in tile
            f32x4 d[4];
            #pragma unroll
            for (int rb = 0; rb < 4; ++rb) d[rb] = (f32x4){0.f, 0.f, 0.f, 0.f};
            #pragma unroll
            for (int k4 = 0; k4 < 4; ++k4) {
                bf16x8 bfr = *(const bf16x8*)(&sB[br * 128 + (((quad + k4 * 4) ^ (br & 7)) << 3)]);
                #pragma unroll
                for (int rb = 0; rb < 4; ++rb)
                    d[rb] = __builtin_amdgcn_mfma_f32_16x16x32_bf16(afr[rb][k4], bfr, d[rb], 0, 0, 0);
            }
            // d[rb][r] = log2(e) * x_{rowbase+rb*16+quad*4+r} . x_{jbase+nt*16+col}
            #pragma unroll
            for (int rb = 0; rb < 4; ++rb)
                #pragma unroll
                for (int r = 0; r < 4; ++r)
                    rs[rb][r] += __builtin_amdgcn_exp2f(d[rb][r]);
        }
    }

    // reduce across the 16 column-lanes within each quad group
    #pragma unroll
    for (int m = 1; m < 16; m <<= 1)
        #pragma unroll
        for (int rb = 0; rb < 4; ++rb)
            #pragma unroll
            for (int r = 0; r < 4; ++r)
                rs[rb][r] += __shfl_xor(rs[rb][r], m);

    if (col == 0) {
        #pragma unroll
        for (int rb = 0; rb < 4; ++rb)
            #pragma unroll
            for (int r = 0; r < 4; ++r)
                atomicAdd(&part[rowbase + rb * 16 + quad * 4 + r], rs[rb][r]);
    }
}

// Kernel C1: one block per batch, 128 threads (one per token).
__global__ __launch_bounds__(128) void fin1_kernel(const float* __restrict__ part,
                                                   const float* __restrict__ pos,
                                                   const int* __restrict__ dia,
                                                   float* __restrict__ bpart) {
    __shared__ float s2[2];
    int b = blockIdx.x;
    int t = threadIdx.x;
    int len = dia[b];
    int i = b * T_LEN + t;
    float acc = (t < len - 1) ? (__logf(part[i]) - pos[i]) : 0.f;
    for (int m = 32; m; m >>= 1) acc += __shfl_xor(acc, m);
    if ((t & 63) == 0) s2[t >> 6] = acc;
    __syncthreads();
    if (t == 0) bpart[b] = s2[0] + s2[1];
}

// Kernel C2: one wave; final sum + divide by total valid count.
__global__ __launch_bounds__(64) void fin2_kernel(const float* __restrict__ bpart,
                                                  const int* __restrict__ dia,
                                                  float* __restrict__ out) {
    int l = threadIdx.x;
    float s = bpart[l];
    int c = dia[l] - 1;
    for (int m = 32; m; m >>= 1) {
        s += __shfl_xor(s, m);
        c += __shfl_xor(c, m);
    }
    if (l == 0) out[0] = s / (float)c;
}

extern "C" void kernel_launch(void* const* d_in, const int* in_sizes, int n_in,
                              void* d_out, int out_size, void* d_ws, size_t ws_size,
                              hipStream_t stream) {
    const float* hs  = (const float*)d_in[0];
    // d_in[1] = mask (implied by dia_lens; unused)
    const int*   dia = (const int*)d_in[2];
    float* out = (float*)d_out;

    ushort_t* xbf = (ushort_t*)d_ws;                                   // 2 MB
    float* pos    = (float*)((char*)d_ws + 2097152);                   // 32 KB
    float* part   = (float*)((char*)d_ws + 2097152 + 32768);           // 32 KB
    float* bpart  = (float*)((char*)d_ws + 2097152 + 65536);           // 256 B

    prep_kernel<<<M_TOK / 4, 256, 0, stream>>>(hs, xbf, pos, part);
    negsum_kernel<<<dim3(M_TOK / 256, JSPLIT), 256, 0, stream>>>(xbf, part);
    fin1_kernel<<<BATCH, 128, 0, stream>>>(part, pos, dia, bpart);
    fin2_kernel<<<1, 64, 0, stream>>>(bpart, dia, out);
}

// Round 3
// 86.767 us; speedup vs baseline: 1.3919x; 1.0304x over previous
//
#include <hip/hip_runtime.h>

typedef __bf16 bf16x8 __attribute__((ext_vector_type(8)));
typedef float  f32x4  __attribute__((ext_vector_type(4)));
typedef unsigned short ushort_t;

#define T_LEN 128
#define BATCH 64
#define M_TOK 8192   // BATCH * T_LEN
#define HDIM  128
#define JSPLIT 32
#define SQRT_LOG2E 1.2011224087864498f  // sqrt(log2(e)); (s*xi).(s*xj) = log2(e)*xi.xj

// round-to-nearest-even fp32 -> bf16
__device__ inline ushort_t f2bf(float f) {
    unsigned int u = __float_as_uint(f);
    unsigned int r = (u + 0x7FFFu + ((u >> 16) & 1u)) >> 16;
    return (ushort_t)r;
}

// async global->LDS, 16B per lane; LDS dest is wave-uniform base + lane*16
__device__ inline void gload_lds16(const ushort_t* g, ushort_t* l) {
    __builtin_amdgcn_global_load_lds(
        (const __attribute__((address_space(1))) void*)g,
        (__attribute__((address_space(3))) void*)l, 16, 0, 0);
}

// Kernel A: 2048 blocks x 256 threads; wave w handles row blockIdx*4+w.
// bf16-convert (pre-scaled by sqrt(log2 e)) + fp32-exact pos_i.
__global__ __launch_bounds__(256) void prep_kernel(const float* __restrict__ hs,
                                                   ushort_t* __restrict__ xbf,
                                                   float* __restrict__ pos) {
    int wave = threadIdx.x >> 6;
    int lane = threadIdx.x & 63;
    int i = blockIdx.x * 4 + wave;
    int t = i & (T_LEN - 1);
    const float* row = hs + (size_t)i * HDIM;
    float x0 = row[lane];
    float x1 = row[lane + 64];
    xbf[(size_t)i * HDIM + lane]      = f2bf(x0 * SQRT_LOG2E);
    xbf[(size_t)i * HDIM + lane + 64] = f2bf(x1 * SQRT_LOG2E);
    float acc = 0.f;
    if (t > 0) {
        const float* p = row - HDIM;
        acc += x0 * p[lane] + x1 * p[lane + 64];
    }
    if (t < T_LEN - 1) {
        const float* n = row + HDIM;
        acc += x0 * n[lane] + x1 * n[lane + 64];
    }
    for (int m = 32; m; m >>= 1) acc += __shfl_xor(acc, m);
    if (lane == 0) pos[i] = acc;
}

// Kernel B: grid (32, 32), block 256 = 4 waves. Wave owns 64 rows (register-
// resident A frags); block covers a 256-column slice, staged as 4 x 64-col
// tiles through a DOUBLE-BUFFERED LDS via async global_load_lds (width 16):
// prefetch tile jt+1 is issued before computing tile jt, so the barrier's
// vmcnt drain is ~1000 cyc after issue. XOR swizzle (16B blocks by row&7) is
// applied on the SOURCE address -> LDS write is contiguous (wave base +
// lane*16), LDS reads conflict-free. part[token][32] written directly.
__global__ __launch_bounds__(256, 4) void negsum_kernel(const ushort_t* __restrict__ xbf,
                                                        float* __restrict__ part) {
    __shared__ __align__(16) ushort_t sB[2][64 * 128];  // 2 x 16 KB
    int tid  = threadIdx.x;
    int wave = tid >> 6;
    int lane = tid & 63;
    int col  = lane & 15;
    int quad = lane >> 4;
    int rowbase = blockIdx.x * 256 + wave * 64;
    int gy = blockIdx.y;

    // A fragments: lane holds A[m=col][k = quad*8 + k4*32 + (0..7)]
    bf16x8 afr[4][4];
    #pragma unroll
    for (int rb = 0; rb < 4; ++rb) {
        const ushort_t* ap = xbf + (size_t)(rowbase + rb * 16 + col) * HDIM + quad * 8;
        #pragma unroll
        for (int k4 = 0; k4 < 4; ++k4)
            afr[rb][k4] = *(const bf16x8*)(ap + k4 * 32);
    }

    float rs[4][4];
    #pragma unroll
    for (int rb = 0; rb < 4; ++rb)
        #pragma unroll
        for (int r = 0; r < 4; ++r) rs[rb][r] = 0.f;

    // stage tile jt into sB[buf]; wave w stages rows w*16..w*16+16 (4 KB)
    // instr q: lds = sB[buf] + w*2048 + q*512 (ushorts, wave-uniform);
    //   lane l lands at row r = w*16 + q*4 + (l>>4), block sb = l&15,
    //   sourced from column block c = sb ^ (r&7)  (swizzle on source side)
    auto stage = [&](int jt, int buf) {
        int jbase = gy * 256 + (jt & 3) * 64;
        #pragma unroll
        for (int q = 0; q < 4; ++q) {
            int r = wave * 16 + q * 4 + (lane >> 4);
            int c = (lane & 15) ^ (r & 7);
            const ushort_t* g = xbf + (size_t)(jbase + r) * HDIM + c * 8;
            ushort_t* l = &sB[buf][wave * 2048 + q * 512];
            gload_lds16(g, l);
        }
    };

    stage(0, 0);
    __syncthreads();

    for (int jt = 0; jt < 4; ++jt) {
        if (jt < 3) stage(jt + 1, (jt + 1) & 1);   // async prefetch, in flight during compute
        int buf = jt & 1;
        #pragma unroll
        for (int nt = 0; nt < 4; ++nt) {
            int br = nt * 16 + col;   // gram column within tile
            f32x4 d[4];
            #pragma unroll
            for (int rb = 0; rb < 4; ++rb) d[rb] = (f32x4){0.f, 0.f, 0.f, 0.f};
            #pragma unroll
            for (int k4 = 0; k4 < 4; ++k4) {
                bf16x8 bfr = *(const bf16x8*)(&sB[buf][br * 128 + (((quad + k4 * 4) ^ (br & 7)) << 3)]);
                #pragma unroll
                for (int rb = 0; rb < 4; ++rb)
                    d[rb] = __builtin_amdgcn_mfma_f32_16x16x32_bf16(afr[rb][k4], bfr, d[rb], 0, 0, 0);
            }
            #pragma unroll
            for (int rb = 0; rb < 4; ++rb)
                #pragma unroll
                for (int r = 0; r < 4; ++r)
                    rs[rb][r] += __builtin_amdgcn_exp2f(d[rb][r]);
        }
        __syncthreads();   // drains prefetch (issued ~1000 cyc ago) + frees buf
    }

    // reduce across the 16 column-lanes within each quad group
    #pragma unroll
    for (int m = 1; m < 16; m <<= 1)
        #pragma unroll
        for (int rb = 0; rb < 4; ++rb)
            #pragma unroll
            for (int r = 0; r < 4; ++r)
                rs[rb][r] += __shfl_xor(rs[rb][r], m);

    if (col == 0) {
        #pragma unroll
        for (int rb = 0; rb < 4; ++rb)
            #pragma unroll
            for (int r = 0; r < 4; ++r)
                part[(size_t)(rowbase + rb * 16 + quad * 4 + r) * JSPLIT + gy] = rs[rb][r];
    }
}

// Kernel C1: one block per batch, 128 threads (one per token).
// part[token][32] is contiguous -> 8 x float4 loads.
__global__ __launch_bounds__(128) void fin1_kernel(const float* __restrict__ part,
                                                   const float* __restrict__ pos,
                                                   const int* __restrict__ dia,
                                                   float* __restrict__ bpart) {
    __shared__ float s2[2];
    int b = blockIdx.x;
    int t = threadIdx.x;
    int len = dia[b];
    int i = b * T_LEN + t;
    const f32x4* p = (const f32x4*)(part + (size_t)i * JSPLIT);
    f32x4 v = p[0];
    #pragma unroll
    for (int q = 1; q < 8; ++q) v += p[q];
    float ns = v.x + v.y + v.z + v.w;
    float acc = (t < len - 1) ? (__logf(ns) - pos[i]) : 0.f;
    for (int m = 32; m; m >>= 1) acc += __shfl_xor(acc, m);
    if ((t & 63) == 0) s2[t >> 6] = acc;
    __syncthreads();
    if (t == 0) bpart[b] = s2[0] + s2[1];
}

// Kernel C2: one wave; final sum + divide by total valid count.
__global__ __launch_bounds__(64) void fin2_kernel(const float* __restrict__ bpart,
                                                  const int* __restrict__ dia,
                                                  float* __restrict__ out) {
    int l = threadIdx.x;
    float s = bpart[l];
    int c = dia[l] - 1;
    for (int m = 32; m; m >>= 1) {
        s += __shfl_xor(s, m);
        c += __shfl_xor(c, m);
    }
    if (l == 0) out[0] = s / (float)c;
}

extern "C" void kernel_launch(void* const* d_in, const int* in_sizes, int n_in,
                              void* d_out, int out_size, void* d_ws, size_t ws_size,
                              hipStream_t stream) {
    const float* hs  = (const float*)d_in[0];
    // d_in[1] = mask (implied by dia_lens; unused)
    const int*   dia = (const int*)d_in[2];
    float* out = (float*)d_out;

    ushort_t* xbf = (ushort_t*)d_ws;                                   // 2 MB
    float* pos    = (float*)((char*)d_ws + 2097152);                   // 32 KB
    float* part   = (float*)((char*)d_ws + 2097152 + 32768);           // 1 MB [token][32]
    float* bpart  = (float*)((char*)d_ws + 2097152 + 32768 + 1048576); // 256 B

    prep_kernel<<<M_TOK / 4, 256, 0, stream>>>(hs, xbf, pos);
    negsum_kernel<<<dim3(M_TOK / 256, JSPLIT), 256, 0, stream>>>(xbf, part);
    fin1_kernel<<<BATCH, 128, 0, stream>>>(part, pos, dia, bpart);
    fin2_kernel<<<1, 64, 0, stream>>>(bpart, dia, out);
}